// Round 2
// baseline (853.393 us; speedup 1.0000x reference)
//
#include <hip/hip_runtime.h>
#include <hip/hip_bf16.h>

#define T_ 1024
#define H_ 1024
#define I_ 512
#define E_ 64
#define S_ 2
#define NJOB 66              // 64 routed + 2 shared "jobs"
#define KSEL 8
#define GRP 8
#define GSIZE 8
#define TKG 4
#define ROWS_TOTAL (T_*KSEL + S_*T_)   // 10240

#define BM 128
#define BN 64
#define LDB 72               // LDS B row stride in shorts (144B, 16B-aligned)

typedef __attribute__((ext_vector_type(8))) __bf16 bf16x8;
typedef __attribute__((ext_vector_type(8))) unsigned short u16x8;
typedef __attribute__((ext_vector_type(4))) unsigned short u16x4;
typedef __attribute__((ext_vector_type(4))) float f32x4;

__device__ inline unsigned short f2bf(float f) {
    unsigned u = __float_as_uint(f);
    u += 0x7FFFu + ((u >> 16) & 1u);   // round-to-nearest-even
    return (unsigned short)(u >> 16);
}

// ---------------- x -> bf16 ----------------
__global__ __launch_bounds__(256) void cvt_x_kernel(const float* __restrict__ x,
                                                    unsigned short* __restrict__ xb) {
    int i = (blockIdx.x * 256 + threadIdx.x) * 4;
    f32x4 v = *(const f32x4*)(x + i);
    u16x4 o;
    o[0] = f2bf(v[0]); o[1] = f2bf(v[1]); o[2] = f2bf(v[2]); o[3] = f2bf(v[3]);
    *(u16x4*)(xb + i) = o;
}

// ---------------- gating: LDS-tiled fp32 logits + grouped top-k ----------------
// 256 blocks x 4 tokens each. gate_w staged transposed in LDS (coalesced global
// reads, conflict-free inner-loop reads).
__global__ __launch_bounds__(256) void gate_kernel(const float* __restrict__ x,
                                                   const float* __restrict__ gate_w,
                                                   int* __restrict__ counts,
                                                   int* __restrict__ topk_idx,
                                                   float* __restrict__ topk_w) {
    __shared__ float Wt[64 * 65];   // [k][e], pad 65
    __shared__ float Xs[4 * 65];    // [tok][k]
    __shared__ float lg[4 * 65];    // [tok][e]

    int tid = threadIdx.x;
    int t0 = blockIdx.x * 4;
    int e = tid & 63;
    int wq = tid >> 6;              // 0..3: token within block / wave id
    int er = tid >> 2;              // 0..63: W row this thread stages
    int kq = (tid & 3) * 16;        // k-offset within chunk this thread stages
    int xk = tid & 63;

    float acc = 0.f;
    for (int kc = 0; kc < 16; ++kc) {
        const float* wp = gate_w + er * H_ + kc * 64 + kq;
        f32x4 w0 = *(const f32x4*)(wp);
        f32x4 w1 = *(const f32x4*)(wp + 4);
        f32x4 w2 = *(const f32x4*)(wp + 8);
        f32x4 w3 = *(const f32x4*)(wp + 12);
        float xv = x[(size_t)(t0 + wq) * H_ + kc * 64 + xk];
        __syncthreads();           // protect previous chunk's reads
#pragma unroll
        for (int i = 0; i < 4; ++i) {
            Wt[(kq + i) * 65 + er] = w0[i];
            Wt[(kq + 4 + i) * 65 + er] = w1[i];
            Wt[(kq + 8 + i) * 65 + er] = w2[i];
            Wt[(kq + 12 + i) * 65 + er] = w3[i];
        }
        Xs[wq * 65 + xk] = xv;
        __syncthreads();
#pragma unroll 8
        for (int k = 0; k < 64; ++k)
            acc += Wt[k * 65 + e] * Xs[wq * 65 + k];
    }
    lg[wq * 65 + e] = acc;
    __syncthreads();

    if (tid < 4) {
        int t = t0 + tid;
        const float* L = &lg[tid * 65];
        float cv[GRP * TKG];
        int   ce[GRP * TKG];
        for (int g = 0; g < GRP; ++g) {
            unsigned used = 0;
            for (int r = 0; r < TKG; ++r) {
                float best = -INFINITY; int bi = 0;
                for (int j = 0; j < GSIZE; ++j) {
                    if (used & (1u << j)) continue;
                    float v = L[g * GSIZE + j];
                    if (v > best) { best = v; bi = j; }
                }
                used |= 1u << bi;
                cv[g * TKG + r] = best;
                ce[g * TKG + r] = g * GSIZE + bi;
            }
        }
        float sv[KSEL]; int si[KSEL];
        unsigned used = 0;
        float sum = 0.0f;
        for (int r = 0; r < KSEL; ++r) {
            float best = -INFINITY; int bi = 0;
            for (int j = 0; j < GRP * TKG; ++j) {
                if (used & (1u << j)) continue;
                if (cv[j] > best) { best = cv[j]; bi = j; }
            }
            used |= 1u << bi;
            sv[r] = best; si[r] = ce[bi];
            sum += best;
        }
        float inv = 1.0f / (sum + 1e-20f);
        for (int r = 0; r < KSEL; ++r) {
            topk_idx[t * KSEL + r] = si[r];
            topk_w[t * KSEL + r] = sv[r] * inv;
            atomicAdd(&counts[si[r]], 1);
        }
    }
}

// ---------------- prefix sum over 66 job counts ----------------
__global__ void prefix_kernel(int* __restrict__ counts, int* __restrict__ offsets,
                              int* __restrict__ cursor) {
    if (threadIdx.x == 0) {
        counts[E_] = T_;
        counts[E_ + 1] = T_;
        int acc = 0;
        for (int j = 0; j < NJOB; ++j) {
            offsets[j] = acc;
            cursor[j] = acc;
            acc += counts[j];
        }
        offsets[NJOB] = acc;
    }
}

// ---------------- scatter (token, weight) into compact per-job segments ----------------
__global__ __launch_bounds__(256) void place_kernel(const int* __restrict__ topk_idx,
                                                    const float* __restrict__ topk_w,
                                                    const int* __restrict__ offsets,
                                                    int* __restrict__ cursor,
                                                    int* __restrict__ row_token,
                                                    float* __restrict__ row_w) {
    int p = blockIdx.x * 256 + threadIdx.x;
    if (p < T_ * KSEL) {
        int t = p >> 3;
        int e = topk_idx[p];
        int slot = atomicAdd(&cursor[e], 1);
        row_token[slot] = t;
        row_w[slot] = topk_w[p];
    } else if (p < T_ * KSEL + S_ * T_) {
        int q = p - T_ * KSEL;
        int s = q >> 10;
        int t = q & (T_ - 1);
        int slot = offsets[E_ + s] + t;
        row_token[slot] = t;
        row_w[slot] = 1.0f;
    }
}

// ---------------- GEMM1: hidden = silu(x@Wg)*(x@Wu); pipelined B staging ----------------
// A fragments direct from global (xb is L2-resident). B: register prefetch of
// next 64k x 64n x {g,u} fp32 tile -> cvt+transpose -> LDS.
__global__ __launch_bounds__(256) void gateup_kernel(const unsigned short* __restrict__ xb,
                                                     const float* __restrict__ w_gu,
                                                     const float* __restrict__ s_gu,
                                                     const int* __restrict__ offsets,
                                                     const int* __restrict__ row_token,
                                                     unsigned short* __restrict__ hidden) {
    int job = blockIdx.x, mt = blockIdx.y, nt = blockIdx.z;
    int seg = offsets[job];
    int cnt = offsets[job + 1] - seg;
    int m0 = mt * BM;
    if (m0 >= cnt) return;
    const float* Bp = (job < E_) ? (w_gu + (size_t)job * H_ * (2 * I_))
                                 : (s_gu + (size_t)(job - E_) * H_ * (2 * I_));
    int n0 = nt * BN;
    const int N2 = 2 * I_;

    __shared__ unsigned short Bs[2 * BN * LDB];   // 18.4 KB

    int tid = threadIdx.x;
    int wv = tid >> 6, lane = tid & 63, lrow = lane & 15, lq = lane >> 4;

    // per-lane A row pointers (include lq*8 k-offset)
    const unsigned short* arow[2];
#pragma unroll
    for (int rb = 0; rb < 2; ++rb) {
        int r = m0 + wv * 32 + rb * 16 + lrow;
        int gi = seg + (r < cnt ? r : 0);
        arow[rb] = xb + (size_t)row_token[gi] * H_ + lq * 8;
    }

    // B staging map: half=g/u, 128 threads each: 16 n-groups x 8 k-groups
    int half = tid >> 7;
    int h = tid & 127;
    int nb = (h & 15) * 4;
    int kb = (h >> 4) * 8;
    const float* bgp = Bp + (size_t)kb * N2 + (half ? (I_ + n0) : n0) + nb;
    unsigned short* wrow = &Bs[(half * BN + nb) * LDB + kb];
    int stagger = tid & 3;

    f32x4 acc[2][2][4];   // [rb][mat][cb]
    f32x4 zero = {0.f, 0.f, 0.f, 0.f};
#pragma unroll
    for (int a = 0; a < 2; ++a)
#pragma unroll
        for (int b = 0; b < 2; ++b)
#pragma unroll
            for (int c = 0; c < 4; ++c) acc[a][b][c] = zero;

    f32x4 bv[8];
#pragma unroll
    for (int j = 0; j < 8; ++j) bv[j] = *(const f32x4*)(bgp + (size_t)j * N2);

    for (int kt = 0; kt < H_ / 64; ++kt) {
        u16x8 pk[4];
#pragma unroll
        for (int c = 0; c < 4; ++c)
#pragma unroll
            for (int j = 0; j < 8; ++j) pk[c][j] = f2bf(bv[j][c]);
        __syncthreads();
#pragma unroll
        for (int c0 = 0; c0 < 4; ++c0) {
            int c = (c0 + stagger) & 3;
            *(u16x8*)(wrow + c * LDB) = pk[c];
        }
        __syncthreads();

        // A fragment loads for THIS tile — issued before B prefetch so the
        // vmcnt wait on A keeps B loads in flight.
        bf16x8 av[2][2];
#pragma unroll
        for (int rb = 0; rb < 2; ++rb)
#pragma unroll
            for (int kk = 0; kk < 2; ++kk)
                av[rb][kk] = *(const bf16x8*)(arow[rb] + kt * 64 + kk * 32);

        // B prefetch for NEXT tile
        if (kt + 1 < H_ / 64) {
#pragma unroll
            for (int j = 0; j < 8; ++j)
                bv[j] = *(const f32x4*)(bgp + (size_t)((kt + 1) * 64 + j) * N2);
        }

        // MFMAs on LDS tile kt
#pragma unroll
        for (int kk = 0; kk < 2; ++kk) {
#pragma unroll
            for (int mat = 0; mat < 2; ++mat) {
                bf16x8 bfr[4];
#pragma unroll
                for (int cb = 0; cb < 4; ++cb)
                    bfr[cb] = *(const bf16x8*)&Bs[(mat * BN + cb * 16 + lrow) * LDB + kk * 32 + lq * 8];
#pragma unroll
                for (int rb = 0; rb < 2; ++rb)
#pragma unroll
                    for (int cb = 0; cb < 4; ++cb)
                        acc[rb][mat][cb] = __builtin_amdgcn_mfma_f32_16x16x32_bf16(
                            av[rb][kk], bfr[cb], acc[rb][mat][cb], 0, 0, 0);
            }
        }
    }

#pragma unroll
    for (int rb = 0; rb < 2; ++rb)
#pragma unroll
        for (int cb = 0; cb < 4; ++cb)
#pragma unroll
            for (int r = 0; r < 4; ++r) {
                int row = wv * 32 + rb * 16 + lq * 4 + r;
                if (m0 + row < cnt) {
                    float g = acc[rb][0][cb][r];
                    float u = acc[rb][1][cb][r];
                    float hh = g / (1.0f + __expf(-g)) * u;
                    hidden[(size_t)(seg + m0 + row) * I_ + n0 + cb * 16 + lrow] = f2bf(hh);
                }
            }
}

// ---------------- GEMM2: out += w * (hidden @ Wd); same pipelined structure ----------------
__global__ __launch_bounds__(256) void down_kernel(const unsigned short* __restrict__ hidden,
                                                   const float* __restrict__ w_d,
                                                   const float* __restrict__ s_d,
                                                   const int* __restrict__ offsets,
                                                   const int* __restrict__ row_token,
                                                   const float* __restrict__ row_w,
                                                   float* __restrict__ out) {
    int job = blockIdx.x, mt = blockIdx.y, nt = blockIdx.z;
    int seg = offsets[job];
    int cnt = offsets[job + 1] - seg;
    int m0 = mt * BM;
    if (m0 >= cnt) return;
    const float* Bp = (job < E_) ? (w_d + (size_t)job * I_ * H_)
                                 : (s_d + (size_t)(job - E_) * I_ * H_);
    int n0 = nt * BN;

    __shared__ unsigned short Bs[BN * LDB];   // 9.2 KB

    int tid = threadIdx.x;
    int wv = tid >> 6, lane = tid & 63, lrow = lane & 15, lq = lane >> 4;

    const unsigned short* arow[2];
    int arix[2];
#pragma unroll
    for (int rb = 0; rb < 2; ++rb) {
        int r = m0 + wv * 32 + rb * 16 + lrow;
        int gi = seg + (r < cnt ? r : 0);
        arow[rb] = hidden + (size_t)gi * I_ + lq * 8;
        arix[rb] = gi;
        (void)arix;
    }

    int nb = (tid & 15) * 4;
    int kb = (tid >> 4) * 4;      // 0..60
    const float* bdp = Bp + (size_t)kb * H_ + n0 + nb;
    unsigned short* wrow = &Bs[nb * LDB + kb];
    int stagger = tid & 3;

    f32x4 acc[2][4];
    f32x4 zero = {0.f, 0.f, 0.f, 0.f};
#pragma unroll
    for (int a = 0; a < 2; ++a)
#pragma unroll
        for (int c = 0; c < 4; ++c) acc[a][c] = zero;

    f32x4 bv[4];
#pragma unroll
    for (int j = 0; j < 4; ++j) bv[j] = *(const f32x4*)(bdp + (size_t)j * H_);

    for (int kt = 0; kt < I_ / 64; ++kt) {
        u16x4 pk[4];
#pragma unroll
        for (int c = 0; c < 4; ++c)
#pragma unroll
            for (int j = 0; j < 4; ++j) pk[c][j] = f2bf(bv[j][c]);
        __syncthreads();
#pragma unroll
        for (int c0 = 0; c0 < 4; ++c0) {
            int c = (c0 + stagger) & 3;
            *(u16x4*)(wrow + c * LDB) = pk[c];
        }
        __syncthreads();

        bf16x8 av[2][2];
#pragma unroll
        for (int rb = 0; rb < 2; ++rb)
#pragma unroll
            for (int kk = 0; kk < 2; ++kk)
                av[rb][kk] = *(const bf16x8*)(arow[rb] + kt * 64 + kk * 32);

        if (kt + 1 < I_ / 64) {
#pragma unroll
            for (int j = 0; j < 4; ++j)
                bv[j] = *(const f32x4*)(bdp + (size_t)((kt + 1) * 64 + j) * H_);
        }

#pragma unroll
        for (int kk = 0; kk < 2; ++kk) {
            bf16x8 bfr[4];
#pragma unroll
            for (int cb = 0; cb < 4; ++cb)
                bfr[cb] = *(const bf16x8*)&Bs[(cb * 16 + lrow) * LDB + kk * 32 + lq * 8];
#pragma unroll
            for (int rb = 0; rb < 2; ++rb)
#pragma unroll
                for (int cb = 0; cb < 4; ++cb)
                    acc[rb][cb] = __builtin_amdgcn_mfma_f32_16x16x32_bf16(
                        av[rb][kk], bfr[cb], acc[rb][cb], 0, 0, 0);
        }
    }

#pragma unroll
    for (int rb = 0; rb < 2; ++rb)
#pragma unroll
        for (int r = 0; r < 4; ++r) {
            int row = wv * 32 + rb * 16 + lq * 4 + r;
            if (m0 + row < cnt) {
                int gi = seg + m0 + row;
                int tok = row_token[gi];
                float w = row_w[gi];
#pragma unroll
                for (int cb = 0; cb < 4; ++cb)
                    atomicAdd(&out[(size_t)tok * H_ + n0 + cb * 16 + lrow],
                              acc[rb][cb][r] * w);
            }
        }
}

extern "C" void kernel_launch(void* const* d_in, const int* in_sizes, int n_in,
                              void* d_out, int out_size, void* d_ws, size_t ws_size,
                              hipStream_t stream) {
    const float* x      = (const float*)d_in[0];
    const float* gate_w = (const float*)d_in[1];
    const float* w_gu   = (const float*)d_in[2];
    const float* w_d    = (const float*)d_in[3];
    const float* s_gu   = (const float*)d_in[4];
    const float* s_d    = (const float*)d_in[5];
    float* out = (float*)d_out;

    char* ws = (char*)d_ws;
    size_t off = 0;
    auto carve = [&](size_t bytes) -> void* {
        void* p = ws + off;
        off += (bytes + 255) & ~(size_t)255;
        return p;
    };
    int* counts            = (int*)carve(NJOB * 4);
    int* offsets           = (int*)carve((NJOB + 1) * 4);
    int* cursor            = (int*)carve(NJOB * 4);
    int* topk_idx          = (int*)carve(T_ * KSEL * 4);
    float* topk_w          = (float*)carve(T_ * KSEL * 4);
    int* row_token         = (int*)carve(ROWS_TOTAL * 4);
    float* row_w           = (float*)carve(ROWS_TOTAL * 4);
    unsigned short* xb     = (unsigned short*)carve((size_t)T_ * H_ * 2);
    unsigned short* hidden = (unsigned short*)carve((size_t)ROWS_TOTAL * I_ * 2);

    hipMemsetAsync(out, 0, (size_t)T_ * H_ * 4, stream);
    hipMemsetAsync(counts, 0, NJOB * 4, stream);

    cvt_x_kernel<<<(T_ * H_ / 4) / 256, 256, 0, stream>>>(x, xb);
    gate_kernel<<<T_ / 4, 256, 0, stream>>>(x, gate_w, counts, topk_idx, topk_w);
    prefix_kernel<<<1, 64, 0, stream>>>(counts, offsets, cursor);
    place_kernel<<<(ROWS_TOTAL + 255) / 256, 256, 0, stream>>>(topk_idx, topk_w, offsets,
                                                               cursor, row_token, row_w);
    gateup_kernel<<<dim3(NJOB, T_ / BM, I_ / BN), 256, 0, stream>>>(xb, w_gu, s_gu, offsets,
                                                                    row_token, hidden);
    down_kernel<<<dim3(NJOB, T_ / BM, H_ / BN), 256, 0, stream>>>(hidden, w_d, s_d, offsets,
                                                                  row_token, row_w, out);
}

// Round 3
// 696.622 us; speedup vs baseline: 1.2250x; 1.2250x over previous
//
#include <hip/hip_runtime.h>
#include <hip/hip_bf16.h>

#define T_ 1024
#define H_ 1024
#define I_ 512
#define E_ 64
#define S_ 2
#define NJOB 66              // 64 routed + 2 shared "jobs"
#define KSEL 8
#define GRP 8
#define GSIZE 8
#define TKG 4
#define ROWS_TOTAL (T_*KSEL + S_*T_)   // 10240

typedef __attribute__((ext_vector_type(8))) __bf16 bf16x8;
typedef __attribute__((ext_vector_type(8))) unsigned short u16x8;
typedef __attribute__((ext_vector_type(4))) unsigned short u16x4;
typedef __attribute__((ext_vector_type(4))) float f32x4;

__device__ inline unsigned short f2bf(float f) {
    unsigned u = __float_as_uint(f);
    u += 0x7FFFu + ((u >> 16) & 1u);   // round-to-nearest-even
    return (unsigned short)(u >> 16);
}

// async global->LDS, 16B per lane. LDS dest must be wave_base + lane*16.
__device__ inline void async16(const void* g, void* l) {
    __builtin_amdgcn_global_load_lds(
        (const __attribute__((address_space(1))) unsigned int*)g,
        (__attribute__((address_space(3))) unsigned int*)(uintptr_t)l,
        16, 0, 0);
}

// ---------------- x -> bf16 ----------------
__global__ __launch_bounds__(256) void cvt_x_kernel(const float* __restrict__ x,
                                                    unsigned short* __restrict__ xb) {
    int i = (blockIdx.x * 256 + threadIdx.x) * 4;
    f32x4 v = *(const f32x4*)(x + i);
    u16x4 o;
    o[0] = f2bf(v[0]); o[1] = f2bf(v[1]); o[2] = f2bf(v[2]); o[3] = f2bf(v[3]);
    *(u16x4*)(xb + i) = o;
}

// ---------------- transpose+convert: src [B][K][N] fp32 -> dst [B][N][K] bf16 ----------------
__global__ __launch_bounds__(256) void cvtT_kernel(const float* __restrict__ src,
                                                   unsigned short* __restrict__ dst,
                                                   int K, int N) {
    int b = blockIdx.z;
    int n0 = blockIdx.x * 64, k0 = blockIdx.y * 64;
    __shared__ unsigned short Lt[64 * 68];
    const float* S = src + ((size_t)b * K + k0) * N + n0;
    unsigned short* D = dst + ((size_t)b * N + n0) * K + k0;
    int t = threadIdx.x;
    int kr = t >> 4;            // 0..15
    int nc = (t & 15) * 4;
#pragma unroll
    for (int p = 0; p < 4; ++p) {
        f32x4 v = *(const f32x4*)(S + (size_t)(kr + p * 16) * N + nc);
#pragma unroll
        for (int j = 0; j < 4; ++j) Lt[(nc + j) * 68 + kr + p * 16] = f2bf(v[j]);
    }
    __syncthreads();
    int nr = t >> 2;            // 0..63
    int kc = (t & 3) * 8;
#pragma unroll
    for (int p = 0; p < 2; ++p) {
        u16x8 o;
#pragma unroll
        for (int j = 0; j < 8; ++j) o[j] = Lt[nr * 68 + kc + p * 32 + j];
        *(u16x8*)(D + (size_t)nr * K + kc + p * 32) = o;
    }
}

// ---------------- gating: LDS-tiled fp32 logits + grouped top-k ----------------
__global__ __launch_bounds__(256) void gate_kernel(const float* __restrict__ x,
                                                   const float* __restrict__ gate_w,
                                                   int* __restrict__ counts,
                                                   int* __restrict__ topk_idx,
                                                   float* __restrict__ topk_w) {
    __shared__ float Wt[64 * 65];
    __shared__ float Xs[4 * 65];
    __shared__ float lg[4 * 65];

    int tid = threadIdx.x;
    int t0 = blockIdx.x * 4;
    int e = tid & 63;
    int wq = tid >> 6;
    int er = tid >> 2;
    int kq = (tid & 3) * 16;
    int xk = tid & 63;

    float acc = 0.f;
    for (int kc = 0; kc < 16; ++kc) {
        const float* wp = gate_w + er * H_ + kc * 64 + kq;
        f32x4 w0 = *(const f32x4*)(wp);
        f32x4 w1 = *(const f32x4*)(wp + 4);
        f32x4 w2 = *(const f32x4*)(wp + 8);
        f32x4 w3 = *(const f32x4*)(wp + 12);
        float xv = x[(size_t)(t0 + wq) * H_ + kc * 64 + xk];
        __syncthreads();
#pragma unroll
        for (int i = 0; i < 4; ++i) {
            Wt[(kq + i) * 65 + er] = w0[i];
            Wt[(kq + 4 + i) * 65 + er] = w1[i];
            Wt[(kq + 8 + i) * 65 + er] = w2[i];
            Wt[(kq + 12 + i) * 65 + er] = w3[i];
        }
        Xs[wq * 65 + xk] = xv;
        __syncthreads();
#pragma unroll 8
        for (int k = 0; k < 64; ++k)
            acc += Wt[k * 65 + e] * Xs[wq * 65 + k];
    }
    lg[wq * 65 + e] = acc;
    __syncthreads();

    if (tid < 4) {
        int t = t0 + tid;
        const float* L = &lg[tid * 65];
        float cv[GRP * TKG];
        int   ce[GRP * TKG];
        for (int g = 0; g < GRP; ++g) {
            unsigned used = 0;
            for (int r = 0; r < TKG; ++r) {
                float best = -INFINITY; int bi = 0;
                for (int j = 0; j < GSIZE; ++j) {
                    if (used & (1u << j)) continue;
                    float v = L[g * GSIZE + j];
                    if (v > best) { best = v; bi = j; }
                }
                used |= 1u << bi;
                cv[g * TKG + r] = best;
                ce[g * TKG + r] = g * GSIZE + bi;
            }
        }
        float sv[KSEL]; int si[KSEL];
        unsigned used = 0;
        float sum = 0.0f;
        for (int r = 0; r < KSEL; ++r) {
            float best = -INFINITY; int bi = 0;
            for (int j = 0; j < GRP * TKG; ++j) {
                if (used & (1u << j)) continue;
                if (cv[j] > best) { best = cv[j]; bi = j; }
            }
            used |= 1u << bi;
            sv[r] = best; si[r] = ce[bi];
            sum += best;
        }
        float inv = 1.0f / (sum + 1e-20f);
        for (int r = 0; r < KSEL; ++r) {
            topk_idx[t * KSEL + r] = si[r];
            topk_w[t * KSEL + r] = sv[r] * inv;
            atomicAdd(&counts[si[r]], 1);
        }
    }
}

// ---------------- prefix sum over 66 job counts ----------------
__global__ void prefix_kernel(int* __restrict__ counts, int* __restrict__ offsets,
                              int* __restrict__ cursor) {
    if (threadIdx.x == 0) {
        counts[E_] = T_;
        counts[E_ + 1] = T_;
        int acc = 0;
        for (int j = 0; j < NJOB; ++j) {
            offsets[j] = acc;
            cursor[j] = acc;
            acc += counts[j];
        }
        offsets[NJOB] = acc;
    }
}

// ---------------- scatter (token, weight) into compact per-job segments ----------------
__global__ __launch_bounds__(256) void place_kernel(const int* __restrict__ topk_idx,
                                                    const float* __restrict__ topk_w,
                                                    const int* __restrict__ offsets,
                                                    int* __restrict__ cursor,
                                                    int* __restrict__ row_token,
                                                    float* __restrict__ row_w) {
    int p = blockIdx.x * 256 + threadIdx.x;
    if (p < T_ * KSEL) {
        int t = p >> 3;
        int e = topk_idx[p];
        int slot = atomicAdd(&cursor[e], 1);
        row_token[slot] = t;
        row_w[slot] = topk_w[p];
    } else if (p < T_ * KSEL + S_ * T_) {
        int q = p - T_ * KSEL;
        int s = q >> 10;
        int t = q & (T_ - 1);
        int slot = offsets[E_ + s] + t;
        row_token[slot] = t;
        row_w[slot] = 1.0f;
    }
}

// ---------------- GEMM1: hidden = silu(x@Wg)*(x@Wu); all-bf16, global_load_lds ----------------
// A: gathered xb rows [128 x 64k]; B: Wt rows (n-major, k-contig) [64 x 64k] x {g,u}.
// LDS XOR-swizzle: chunk (row, c) holds global chunk (row, c ^ (row&7)).
__global__ __launch_bounds__(256) void gateup_kernel(const unsigned short* __restrict__ xb,
                                                     const unsigned short* __restrict__ wgu_t,
                                                     const unsigned short* __restrict__ sgu_t,
                                                     const int* __restrict__ offsets,
                                                     const int* __restrict__ row_token,
                                                     unsigned short* __restrict__ hidden) {
    int job = blockIdx.x, mt = blockIdx.y, nt = blockIdx.z;
    int seg = offsets[job];
    int cnt = offsets[job + 1] - seg;
    int m0 = mt * 128;
    if (m0 >= cnt) return;
    const unsigned short* Wt = (job < E_) ? (wgu_t + (size_t)job * (2 * I_) * H_)
                                          : (sgu_t + (size_t)(job - E_) * (2 * I_) * H_);
    int n0 = nt * 64;

    __shared__ unsigned short As[128 * 64];   // 16 KB
    __shared__ unsigned short Bg[64 * 64];    // 8 KB
    __shared__ unsigned short Bu[64 * 64];    // 8 KB

    int tid = threadIdx.x;
    int wv = tid >> 6, lane = tid & 63, lrow = lane & 15, lq = lane >> 4;

    const unsigned short* asrc[4];
#pragma unroll
    for (int i = 0; i < 4; ++i) {
        int d = i * 256 + tid;            // chunk 0..1023
        int row = d >> 3;
        int kc = (d & 7) ^ (row & 7);
        int r = m0 + row;
        int gi = seg + (r < cnt ? r : 0);
        asrc[i] = xb + (size_t)row_token[gi] * H_ + kc * 8;
    }
    const unsigned short* bgsrc[2];
    const unsigned short* busrc[2];
#pragma unroll
    for (int i = 0; i < 2; ++i) {
        int d = i * 256 + tid;            // chunk 0..511
        int n = d >> 3;
        int kc = (d & 7) ^ (n & 7);
        bgsrc[i] = Wt + (size_t)(n0 + n) * H_ + kc * 8;
        busrc[i] = Wt + (size_t)(I_ + n0 + n) * H_ + kc * 8;
    }

    f32x4 accg[2][4], accu[2][4];
    f32x4 zero = {0.f, 0.f, 0.f, 0.f};
#pragma unroll
    for (int a = 0; a < 2; ++a)
#pragma unroll
        for (int c = 0; c < 4; ++c) { accg[a][c] = zero; accu[a][c] = zero; }

    for (int kt = 0; kt < H_ / 64; ++kt) {
        int ko = kt * 64;
#pragma unroll
        for (int i = 0; i < 4; ++i)
            async16(asrc[i] + ko, &As[(i * 256 + tid) * 8]);
#pragma unroll
        for (int i = 0; i < 2; ++i) {
            async16(bgsrc[i] + ko, &Bg[(i * 256 + tid) * 8]);
            async16(busrc[i] + ko, &Bu[(i * 256 + tid) * 8]);
        }
        __syncthreads();

#pragma unroll
        for (int kk = 0; kk < 2; ++kk) {
            bf16x8 a[2];
#pragma unroll
            for (int rb = 0; rb < 2; ++rb) {
                int R = wv * 32 + rb * 16 + lrow;
                a[rb] = *(const bf16x8*)&As[R * 64 + (((lq + kk * 4) ^ (R & 7)) * 8)];
            }
#pragma unroll
            for (int cb = 0; cb < 4; ++cb) {
                int n = cb * 16 + lrow;
                int koff = ((lq + kk * 4) ^ (n & 7)) * 8;
                bf16x8 bg = *(const bf16x8*)&Bg[n * 64 + koff];
                bf16x8 bu = *(const bf16x8*)&Bu[n * 64 + koff];
#pragma unroll
                for (int rb = 0; rb < 2; ++rb) {
                    accg[rb][cb] = __builtin_amdgcn_mfma_f32_16x16x32_bf16(a[rb], bg, accg[rb][cb], 0, 0, 0);
                    accu[rb][cb] = __builtin_amdgcn_mfma_f32_16x16x32_bf16(a[rb], bu, accu[rb][cb], 0, 0, 0);
                }
            }
        }
        __syncthreads();
    }

#pragma unroll
    for (int rb = 0; rb < 2; ++rb)
#pragma unroll
        for (int cb = 0; cb < 4; ++cb)
#pragma unroll
            for (int r = 0; r < 4; ++r) {
                int row = wv * 32 + rb * 16 + lq * 4 + r;
                if (m0 + row < cnt) {
                    float g = accg[rb][cb][r];
                    float u = accu[rb][cb][r];
                    float hh = g / (1.0f + __expf(-g)) * u;
                    hidden[(size_t)(seg + m0 + row) * I_ + n0 + cb * 16 + lrow] = f2bf(hh);
                }
            }
}

// ---------------- GEMM2: out += w * (hidden @ Wd^T-layout); global_load_lds ----------------
__global__ __launch_bounds__(256) void down_kernel(const unsigned short* __restrict__ hidden,
                                                   const unsigned short* __restrict__ wd_t,
                                                   const unsigned short* __restrict__ sd_t,
                                                   const int* __restrict__ offsets,
                                                   const int* __restrict__ row_token,
                                                   const float* __restrict__ row_w,
                                                   float* __restrict__ out) {
    int job = blockIdx.x, mt = blockIdx.y, nt = blockIdx.z;
    int seg = offsets[job];
    int cnt = offsets[job + 1] - seg;
    int m0 = mt * 128;
    if (m0 >= cnt) return;
    const unsigned short* Wt = (job < E_) ? (wd_t + (size_t)job * H_ * I_)
                                          : (sd_t + (size_t)(job - E_) * H_ * I_);
    int n0 = nt * 64;

    __shared__ unsigned short As[128 * 64];   // 16 KB
    __shared__ unsigned short Bs[64 * 64];    // 8 KB

    int tid = threadIdx.x;
    int wv = tid >> 6, lane = tid & 63, lrow = lane & 15, lq = lane >> 4;

    const unsigned short* asrc[4];
#pragma unroll
    for (int i = 0; i < 4; ++i) {
        int d = i * 256 + tid;
        int row = d >> 3;
        int kc = (d & 7) ^ (row & 7);
        int r = m0 + row;
        int gi = seg + (r < cnt ? r : 0);
        asrc[i] = hidden + (size_t)gi * I_ + kc * 8;
    }
    const unsigned short* bsrc[2];
#pragma unroll
    for (int i = 0; i < 2; ++i) {
        int d = i * 256 + tid;
        int n = d >> 3;
        int kc = (d & 7) ^ (n & 7);
        bsrc[i] = Wt + (size_t)(n0 + n) * I_ + kc * 8;
    }

    f32x4 acc[2][4];
    f32x4 zero = {0.f, 0.f, 0.f, 0.f};
#pragma unroll
    for (int a = 0; a < 2; ++a)
#pragma unroll
        for (int c = 0; c < 4; ++c) acc[a][c] = zero;

    for (int kt = 0; kt < I_ / 64; ++kt) {
        int ko = kt * 64;
#pragma unroll
        for (int i = 0; i < 4; ++i)
            async16(asrc[i] + ko, &As[(i * 256 + tid) * 8]);
#pragma unroll
        for (int i = 0; i < 2; ++i)
            async16(bsrc[i] + ko, &Bs[(i * 256 + tid) * 8]);
        __syncthreads();

#pragma unroll
        for (int kk = 0; kk < 2; ++kk) {
            bf16x8 a[2];
#pragma unroll
            for (int rb = 0; rb < 2; ++rb) {
                int R = wv * 32 + rb * 16 + lrow;
                a[rb] = *(const bf16x8*)&As[R * 64 + (((lq + kk * 4) ^ (R & 7)) * 8)];
            }
#pragma unroll
            for (int cb = 0; cb < 4; ++cb) {
                int n = cb * 16 + lrow;
                bf16x8 b = *(const bf16x8*)&Bs[n * 64 + (((lq + kk * 4) ^ (n & 7)) * 8)];
#pragma unroll
                for (int rb = 0; rb < 2; ++rb)
                    acc[rb][cb] = __builtin_amdgcn_mfma_f32_16x16x32_bf16(a[rb], b, acc[rb][cb], 0, 0, 0);
            }
        }
        __syncthreads();
    }

#pragma unroll
    for (int rb = 0; rb < 2; ++rb)
#pragma unroll
        for (int r = 0; r < 4; ++r) {
            int row = wv * 32 + rb * 16 + lq * 4 + r;
            if (m0 + row < cnt) {
                int gi = seg + m0 + row;
                int tok = row_token[gi];
                float w = row_w[gi];
#pragma unroll
                for (int cb = 0; cb < 4; ++cb)
                    atomicAdd(&out[(size_t)tok * H_ + n0 + cb * 16 + lrow],
                              acc[rb][cb][r] * w);
            }
        }
}

extern "C" void kernel_launch(void* const* d_in, const int* in_sizes, int n_in,
                              void* d_out, int out_size, void* d_ws, size_t ws_size,
                              hipStream_t stream) {
    const float* x      = (const float*)d_in[0];
    const float* gate_w = (const float*)d_in[1];
    const float* w_gu   = (const float*)d_in[2];
    const float* w_d    = (const float*)d_in[3];
    const float* s_gu   = (const float*)d_in[4];
    const float* s_d    = (const float*)d_in[5];
    float* out = (float*)d_out;

    char* ws = (char*)d_ws;
    size_t off = 0;
    auto carve = [&](size_t bytes) -> void* {
        void* p = ws + off;
        off += (bytes + 255) & ~(size_t)255;
        return p;
    };
    int* counts            = (int*)carve(NJOB * 4);
    int* offsets           = (int*)carve((NJOB + 1) * 4);
    int* cursor            = (int*)carve(NJOB * 4);
    int* topk_idx          = (int*)carve(T_ * KSEL * 4);
    float* topk_w          = (float*)carve(T_ * KSEL * 4);
    int* row_token         = (int*)carve(ROWS_TOTAL * 4);
    float* row_w           = (float*)carve(ROWS_TOTAL * 4);
    unsigned short* xb     = (unsigned short*)carve((size_t)T_ * H_ * 2);
    unsigned short* hidden = (unsigned short*)carve((size_t)ROWS_TOTAL * I_ * 2);
    unsigned short* wgu_t  = (unsigned short*)carve((size_t)E_ * (2 * I_) * H_ * 2);  // 134 MB
    unsigned short* wd_t   = (unsigned short*)carve((size_t)E_ * H_ * I_ * 2);        // 67 MB
    unsigned short* sgu_t  = (unsigned short*)carve((size_t)S_ * (2 * I_) * H_ * 2);  // 4.2 MB
    unsigned short* sd_t   = (unsigned short*)carve((size_t)S_ * H_ * I_ * 2);        // 2.1 MB

    hipMemsetAsync(out, 0, (size_t)T_ * H_ * 4, stream);
    hipMemsetAsync(counts, 0, NJOB * 4, stream);

    cvt_x_kernel<<<(T_ * H_ / 4) / 256, 256, 0, stream>>>(x, xb);
    // weight transpose+convert: src [B][K][N] -> dst [B][N][K] bf16
    cvtT_kernel<<<dim3((2 * I_) / 64, H_ / 64, E_), 256, 0, stream>>>(w_gu, wgu_t, H_, 2 * I_);
    cvtT_kernel<<<dim3(H_ / 64, I_ / 64, E_), 256, 0, stream>>>(w_d, wd_t, I_, H_);
    cvtT_kernel<<<dim3((2 * I_) / 64, H_ / 64, S_), 256, 0, stream>>>(s_gu, sgu_t, H_, 2 * I_);
    cvtT_kernel<<<dim3(H_ / 64, I_ / 64, S_), 256, 0, stream>>>(s_d, sd_t, I_, H_);

    gate_kernel<<<T_ / 4, 256, 0, stream>>>(x, gate_w, counts, topk_idx, topk_w);
    prefix_kernel<<<1, 64, 0, stream>>>(counts, offsets, cursor);
    place_kernel<<<(ROWS_TOTAL + 255) / 256, 256, 0, stream>>>(topk_idx, topk_w, offsets,
                                                               cursor, row_token, row_w);
    gateup_kernel<<<dim3(NJOB, T_ / 128, I_ / 64), 256, 0, stream>>>(xb, wgu_t, sgu_t, offsets,
                                                                     row_token, hidden);
    down_kernel<<<dim3(NJOB, T_ / 128, H_ / 64), 256, 0, stream>>>(hidden, wd_t, sd_t, offsets,
                                                                   row_token, row_w, out);
}